// Round 1
// baseline (706.451 us; speedup 1.0000x reference)
//
#include <hip/hip_runtime.h>

#define NPTS      1048576
#define TABLE_SZ  1048577
#define MAXLVL    12
#define NLEVELS   3
#define FDIM      8

__global__ __launch_bounds__(256) void octree_interp_kernel(
    const float* __restrict__ coord,     // (NPTS, 3)
    const float* __restrict__ features,  // (NLEVELS, TABLE_SZ, 8)
    const int*   __restrict__ indices,   // (NLEVELS, NPTS, 8)
    float*       __restrict__ out)       // (NPTS, 8)
{
    int n = blockIdx.x * blockDim.x + threadIdx.x;
    if (n >= NPTS) return;

    float x = coord[3 * n + 0];
    float y = coord[3 * n + 1];
    float z = coord[3 * n + 2];

    float acc[FDIM];
    #pragma unroll
    for (int d = 0; d < FDIM; ++d) acc[d] = 0.0f;

    #pragma unroll
    for (int i = 0; i < NLEVELS; ++i) {
        const int level  = MAXLVL - i;          // 12, 11, 10
        const int flevel = NLEVELS - 1 - i;     // 2, 1, 0
        const float scale = (float)(1 << (level - 1));  // 2^(level-1)

        // coords = 2^level * (x*0.5 + 0.5) = scale*x + scale
        float cx = fmaf(scale, x, scale);
        float cy = fmaf(scale, y, scale);
        float cz = fmaf(scale, z, scale);
        float dx = cx - floorf(cx);
        float dy = cy - floorf(cy);
        float dz = cz - floorf(cz);
        // smoothstep polynomial 3d^2 - 2d^3
        dx = dx * dx * (3.0f - 2.0f * dx);
        dy = dy * dy * (3.0f - 2.0f * dy);
        dz = dz * dz * (3.0f - 2.0f * dz);

        float wx[2] = {1.0f - dx, dx};
        float wy[2] = {1.0f - dy, dy};
        float wz[2] = {1.0f - dz, dz};

        // 8 int32 indices per point, contiguous: two int4 loads
        const int4* ip = reinterpret_cast<const int4*>(
            indices + ((size_t)i * NPTS + (size_t)n) * 8);
        int4 iv0 = ip[0];
        int4 iv1 = ip[1];
        int idx8[8] = {iv0.x, iv0.y, iv0.z, iv0.w, iv1.x, iv1.y, iv1.z, iv1.w};

        const float* ftab = features + (size_t)flevel * (size_t)TABLE_SZ * FDIM;

        #pragma unroll
        for (int c = 0; c < 8; ++c) {
            // weight order: bit2 -> tx, bit1 -> ty, bit0 -> tz
            float w = wx[(c >> 2) & 1] * wy[(c >> 1) & 1] * wz[c & 1];
            int idx = idx8[c];
            // features[:, -1, :] is zeroed in the reference: mask weight
            w = (idx == TABLE_SZ - 1) ? 0.0f : w;
            const float4* g = reinterpret_cast<const float4*>(
                ftab + (size_t)idx * FDIM);
            float4 g0 = g[0];
            float4 g1 = g[1];
            acc[0] = fmaf(w, g0.x, acc[0]);
            acc[1] = fmaf(w, g0.y, acc[1]);
            acc[2] = fmaf(w, g0.z, acc[2]);
            acc[3] = fmaf(w, g0.w, acc[3]);
            acc[4] = fmaf(w, g1.x, acc[4]);
            acc[5] = fmaf(w, g1.y, acc[5]);
            acc[6] = fmaf(w, g1.z, acc[6]);
            acc[7] = fmaf(w, g1.w, acc[7]);
        }
    }

    float4* op = reinterpret_cast<float4*>(out + (size_t)n * FDIM);
    op[0] = make_float4(acc[0], acc[1], acc[2], acc[3]);
    op[1] = make_float4(acc[4], acc[5], acc[6], acc[7]);
}

extern "C" void kernel_launch(void* const* d_in, const int* in_sizes, int n_in,
                              void* d_out, int out_size, void* d_ws, size_t ws_size,
                              hipStream_t stream) {
    const float* coord    = (const float*)d_in[0];
    const float* features = (const float*)d_in[1];
    const int*   indices  = (const int*)d_in[2];
    float*       out      = (float*)d_out;

    const int block = 256;
    const int grid  = (NPTS + block - 1) / block;
    octree_interp_kernel<<<grid, block, 0, stream>>>(coord, features, indices, out);
}

// Round 2
// 447.780 us; speedup vs baseline: 1.5777x; 1.5777x over previous
//
#include <hip/hip_runtime.h>

#define NPTS      1048576
#define TABLE_SZ  1048577
#define NLEVELS   3
#define FDIM      8

// One lane per (point, corner): 8 lanes cooperate on one point.
// tid = point*8 + corner. All index loads and output stores are coalesced;
// each lane issues all 3 levels' gathers back-to-back (6 dwordx4 in flight).
__global__ __launch_bounds__(256) void octree_gather_kernel(
    const float* __restrict__ coord,     // (NPTS, 3)
    const float* __restrict__ features,  // (NLEVELS, TABLE_SZ, 8)
    const int*   __restrict__ indices,   // (NLEVELS, NPTS, 8)
    float*       __restrict__ out)       // (NPTS, 8)
{
    const int tid    = blockIdx.x * blockDim.x + threadIdx.x;
    const int lane_c = tid & 7;   // corner 0..7
    const int n      = tid >> 3;  // point index

    const float x = coord[3 * n + 0];
    const float y = coord[3 * n + 1];
    const float z = coord[3 * n + 2];

    // ---- load all 3 levels' indices (coalesced: addr = i*NPTS*8 + tid) ----
    int idx[NLEVELS];
    #pragma unroll
    for (int i = 0; i < NLEVELS; ++i)
        idx[i] = indices[(size_t)i * (size_t)NPTS * 8 + (size_t)tid];

    // ---- issue ALL gathers up front (6 dwordx4 in flight per lane) ----
    float4 ga[NLEVELS], gb[NLEVELS];
    #pragma unroll
    for (int i = 0; i < NLEVELS; ++i) {
        const float* ft = features + (size_t)(NLEVELS - 1 - i) * (size_t)TABLE_SZ * FDIM;
        const float4* gp = reinterpret_cast<const float4*>(ft + (size_t)idx[i] * FDIM);
        ga[i] = gp[0];
        gb[i] = gp[1];
    }

    // ---- compute per-level smoothstep weights (overlaps gather latency) ----
    float w[NLEVELS];
    #pragma unroll
    for (int i = 0; i < NLEVELS; ++i) {
        const float scale = (float)(2048 >> i);  // 2^(level-1), level = 12-i
        float cx = fmaf(scale, x, scale);
        float cy = fmaf(scale, y, scale);
        float cz = fmaf(scale, z, scale);
        float dx = cx - floorf(cx);
        float dy = cy - floorf(cy);
        float dz = cz - floorf(cz);
        dx = dx * dx * (3.0f - 2.0f * dx);
        dy = dy * dy * (3.0f - 2.0f * dy);
        dz = dz * dz * (3.0f - 2.0f * dz);
        // weight order: bit2 -> x, bit1 -> y, bit0 -> z
        float wi = ((lane_c & 4) ? dx : 1.0f - dx)
                 * ((lane_c & 2) ? dy : 1.0f - dy)
                 * ((lane_c & 1) ? dz : 1.0f - dz);
        // reference zeroes features[:, -1, :]: mask the weight instead
        w[i] = (idx[i] == TABLE_SZ - 1) ? 0.0f : wi;
    }

    // ---- weighted accumulate over levels ----
    float acc[FDIM];
    #pragma unroll
    for (int d = 0; d < FDIM; ++d) acc[d] = 0.0f;
    #pragma unroll
    for (int i = 0; i < NLEVELS; ++i) {
        acc[0] = fmaf(w[i], ga[i].x, acc[0]);
        acc[1] = fmaf(w[i], ga[i].y, acc[1]);
        acc[2] = fmaf(w[i], ga[i].z, acc[2]);
        acc[3] = fmaf(w[i], ga[i].w, acc[3]);
        acc[4] = fmaf(w[i], gb[i].x, acc[4]);
        acc[5] = fmaf(w[i], gb[i].y, acc[5]);
        acc[6] = fmaf(w[i], gb[i].z, acc[6]);
        acc[7] = fmaf(w[i], gb[i].w, acc[7]);
    }

    // ---- 3-round shfl_xor transpose-reduce over the 8 corner-lanes ----
    // After the 3 rounds, lane c holds output element c of its point.
    const int b0 = lane_c & 1, b1 = (lane_c >> 1) & 1, b2 = (lane_c >> 2) & 1;

    float s4[4];
    #pragma unroll
    for (int j = 0; j < 4; ++j) {
        float snd  = b0 ? acc[2 * j] : acc[2 * j + 1];
        float got  = __shfl_xor(snd, 1);
        float kept = b0 ? acc[2 * j + 1] : acc[2 * j];
        s4[j] = kept + got;   // element (j<<1)|b0, summed over lane-bit0
    }
    float s2[2];
    #pragma unroll
    for (int j = 0; j < 2; ++j) {
        float snd  = b1 ? s4[2 * j] : s4[2 * j + 1];
        float got  = __shfl_xor(snd, 2);
        float kept = b1 ? s4[2 * j + 1] : s4[2 * j];
        s2[j] = kept + got;   // element (j<<2)|(b1<<1)|b0
    }
    {
        float snd  = b2 ? s2[0] : s2[1];
        float got  = __shfl_xor(snd, 4);
        float kept = b2 ? s2[1] : s2[0];
        float s = kept + got; // element (b2<<2)|(b1<<1)|b0 == lane_c
        out[(size_t)n * FDIM + lane_c] = s;  // coalesced 256B per wave
    }
}

extern "C" void kernel_launch(void* const* d_in, const int* in_sizes, int n_in,
                              void* d_out, int out_size, void* d_ws, size_t ws_size,
                              hipStream_t stream) {
    const float* coord    = (const float*)d_in[0];
    const float* features = (const float*)d_in[1];
    const int*   indices  = (const int*)d_in[2];
    float*       out      = (float*)d_out;

    const int block = 256;
    const long total_threads = (long)NPTS * 8;          // one lane per (point, corner)
    const int grid  = (int)((total_threads + block - 1) / block);  // 32768
    octree_gather_kernel<<<grid, block, 0, stream>>>(coord, features, indices, out);
}